// Round 10
// baseline (73.109 us; speedup 1.0000x reference)
//
#include <hip/hip_runtime.h>
#include <math.h>
#include <stdint.h>

#define N_NODES 8192
#define D 7
#define K 32
#define NT 512
#define QB 8
#define CPT (N_NODES / NT)   // 16 j's per thread
#define SUBC 8               // pass-1 subsample: first 4096 nodes
#define ECAP2 256            // rank-candidate capacity (cnt2 p99.99 < 180)
#define DELTA 0.125f         // f16-screen error bound

typedef unsigned long long u64;
typedef _Float16 h2 __attribute__((ext_vector_type(2)));

__device__ __forceinline__ float rfl(float v) {
    return __uint_as_float(__builtin_amdgcn_readfirstlane(__float_as_uint(v)));
}
__device__ __forceinline__ unsigned rflu(unsigned v) {
    return __builtin_amdgcn_readfirstlane(v);
}
__device__ __forceinline__ h2 h2u(unsigned u) {
    union { unsigned u; h2 h; } t; t.u = u; return t.h;
}
__device__ __forceinline__ unsigned pkh(float a, float b) {
    union { h2 h; unsigned u; } t;
    t.h[0] = (_Float16)a; t.h[1] = (_Float16)b; return t.u;
}
// order-preserving float<->uint (total order, handles negatives)
__device__ __forceinline__ unsigned ordu(float f) {
    unsigned u = __float_as_uint(f);
    return (u & 0x80000000u) ? ~u : (u | 0x80000000u);
}
__device__ __forceinline__ float unordu(unsigned o) {
    unsigned u = (o & 0x80000000u) ? (o & 0x7fffffffu) : ~o;
    return __uint_as_float(u);
}

#if __has_builtin(__builtin_amdgcn_fdot2)
#define FDOT2(a, b, c) __builtin_amdgcn_fdot2((a), (b), (c), false)
#else
__device__ __forceinline__ float FDOT2(h2 a, h2 b, float c) {
    return fmaf((float)a[1], (float)b[1], fmaf((float)a[0], (float)b[0], c));
}
#endif

// exact m = sqj - 2*dot(fi, fj); identical rounding chain at every call site
// (matches all prior passing rounds). B.w unused in the dot.
__device__ __forceinline__ float dist_m(float4 b0, float4 b1, float sqj,
                                        float4 A, float4 B) {
    float dot = A.x * b0.x;
    dot = fmaf(A.y, b0.y, dot);
    dot = fmaf(A.z, b0.z, dot);
    dot = fmaf(A.w, b0.w, dot);
    dot = fmaf(B.x, b1.x, dot);
    dot = fmaf(B.y, b1.y, dot);
    dot = fmaf(B.z, b1.z, dot);
    return fmaf(-2.0f, dot, sqj);
}

// f16 screen m via packed dot2 chain.
__device__ __forceinline__ float screen_m(uint4 dj, unsigned s0, unsigned s1,
                                          unsigned s2, unsigned s3) {
    return FDOT2(h2u(dj.x), h2u(s0),
           FDOT2(h2u(dj.y), h2u(s1),
           FDOT2(h2u(dj.z), h2u(s2),
           FDOT2(h2u(dj.w), h2u(s3), 0.f))));
}

// ---------------------------------------------------------------------------
// Kernel 1: outb = clip(feat @ W^T), fh = packed f16 [f0..f6,sq] (16 B/node),
//           xsq = packed f32 [f0..f6, sq] (32 B/node).
// ---------------------------------------------------------------------------
__global__ __launch_bounds__(256)
void precompute_kernel(const float* __restrict__ x, const float* __restrict__ W,
                       float* __restrict__ outb, uint4* __restrict__ fh,
                       float4* __restrict__ xsq4)
{
    int n = blockIdx.x * 256 + threadIdx.x;
    float4 v0 = *reinterpret_cast<const float4*>(x + n * 8);
    float4 v1 = *reinterpret_cast<const float4*>(x + n * 8 + 4);
    float f[D] = {v0.x, v0.y, v0.z, v0.w, v1.x, v1.y, v1.z};
    float sq = 0.f;
#pragma unroll
    for (int c = 0; c < D; ++c) sq += f[c] * f[c];
    uint4 h;
    h.x = pkh(f[0], f[1]); h.y = pkh(f[2], f[3]);
    h.z = pkh(f[4], f[5]); h.w = pkh(f[6], sq);
    fh[n] = h;
    xsq4[n * 2]     = v0;
    xsq4[n * 2 + 1] = make_float4(v1.x, v1.y, v1.z, sq);
#pragma unroll
    for (int r = 0; r < D; ++r) {
        float acc = 0.f;
#pragma unroll
        for (int c = 0; c < D; ++c) acc += f[c] * W[r * D + c];
        acc = fminf(fmaxf(acc, -1.f), 1.f);
        outb[n * D + r] = acc;
    }
}

// ---------------------------------------------------------------------------
// Kernel 2: exact top-32 (jax.lax.top_k order) + attention.
// Half-sample f16 screen -> 34th-of-512 ballot-bisect threshold T ->
// ONE exact fp32 pass keeping m <= T+DELTA straight into rank buffer.
// ---------------------------------------------------------------------------
__global__ __launch_bounds__(NT, 4)
void gat_kernel(const float* __restrict__ x, const float* __restrict__ aw,
                const float* __restrict__ outb, const uint4* __restrict__ fh,
                const float4* __restrict__ xs4, float* __restrict__ dout)
{
    __shared__ u64      cand[QB][ECAP2];     // 16 KB, aliases Lmin
    __shared__ int      nbr[QB][K];
    __shared__ unsigned selT[QB];
    __shared__ int      cnt2[QB];
    __shared__ float    redv[8];
    __shared__ int      redi[8];
    __shared__ float    bcv;
    __shared__ int      bci;

    float* Lmin = (float*)cand;              // [QB][NT] raw lane-mins (16 KB)

    const int tid  = threadIdx.x;
    const int lane = tid & 63;
    const int wave = tid >> 6;
    const int i0   = blockIdx.x * QB;

    // query scalars (static indexing only): f16-packed for pass 1,
    // f32 float4 pair for the exact pass.
    unsigned qs0[QB], qs1[QB], qs2[QB], qs3[QB];
    float4 qA[QB], qBv[QB];
    float sqi[QB];
#pragma unroll
    for (int q = 0; q < QB; ++q) {
        const float* xq = x + (i0 + q) * 8;
        float4 a0 = *reinterpret_cast<const float4*>(xq);
        float4 a1 = *reinterpret_cast<const float4*>(xq + 4);
        float sq_ = rfl(xs4[(i0 + q) * 2 + 1].w);
        qs0[q] = rflu(pkh(-2.f * a0.x, -2.f * a0.y));
        qs1[q] = rflu(pkh(-2.f * a0.z, -2.f * a0.w));
        qs2[q] = rflu(pkh(-2.f * a1.x, -2.f * a1.y));
        qs3[q] = rflu(pkh(-2.f * a1.z, 1.0f));
        qA[q].x  = rfl(a0.x); qA[q].y  = rfl(a0.y);
        qA[q].z  = rfl(a0.z); qA[q].w  = rfl(a0.w);
        qBv[q].x = rfl(a1.x); qBv[q].y = rfl(a1.y);
        qBv[q].z = rfl(a1.z); qBv[q].w = sq_;
        sqi[q]   = sq_;
    }
    if (tid < QB) cnt2[tid] = 0;

    // ---- pass 1: f16 screen over HALF-SAMPLE (nodes 0..4095), lane-min ----
    float lm[QB];
#pragma unroll
    for (int q = 0; q < QB; ++q) lm[q] = INFINITY;

#pragma unroll 4
    for (int c = 0; c < SUBC; ++c) {
        uint4 dj = fh[c * NT + tid];
#pragma unroll
        for (int q = 0; q < QB; ++q)
            lm[q] = fminf(lm[q], screen_m(dj, qs0[q], qs1[q], qs2[q], qs3[q]));
    }
#pragma unroll
    for (int q = 0; q < QB; ++q) Lmin[q * NT + tid] = lm[q];
    __syncthreads();

    // ---- EXACT 34th-smallest of 512 lane-mins (wave w -> query w) ----
    // 34 (not 33): one lane-min may be the diagonal -> still >=33 distinct
    // non-diag screen values <= T. Ballot-bisection, register-resident.
    {
        const int q = wave;
        unsigned ov0 = ordu(Lmin[q * NT +   0 + lane]);
        unsigned ov1 = ordu(Lmin[q * NT +  64 + lane]);
        unsigned ov2 = ordu(Lmin[q * NT + 128 + lane]);
        unsigned ov3 = ordu(Lmin[q * NT + 192 + lane]);
        unsigned ov4 = ordu(Lmin[q * NT + 256 + lane]);
        unsigned ov5 = ordu(Lmin[q * NT + 320 + lane]);
        unsigned ov6 = ordu(Lmin[q * NT + 384 + lane]);
        unsigned ov7 = ordu(Lmin[q * NT + 448 + lane]);
        unsigned lo = 0u, hi = 0xFFFFFFFFu;
        while (lo < hi) {
            unsigned mid = lo + ((hi - lo) >> 1);
            int cnt = __popcll(__ballot(ov0 <= mid))
                    + __popcll(__ballot(ov1 <= mid))
                    + __popcll(__ballot(ov2 <= mid))
                    + __popcll(__ballot(ov3 <= mid))
                    + __popcll(__ballot(ov4 <= mid))
                    + __popcll(__ballot(ov5 <= mid))
                    + __popcll(__ballot(ov6 <= mid))
                    + __popcll(__ballot(ov7 <= mid));
            if (cnt >= 34) hi = mid; else lo = mid + 1;
        }
        if (lane == 0) selT[q] = lo;
    }
    __syncthreads();

    // exact-keep threshold: >=33 non-diag f16-screens <= T => their exacts
    // <= T+DELTA => exact 32nd <= T+DELTA. Clamp-to-zero region via -sqi.
    float exq[QB];
#pragma unroll
    for (int q = 0; q < QB; ++q)
        exq[q] = fmaxf(unordu(selT[q]) + DELTA, -sqi[q]);

    // ---- pass 2: ONE exact fp32 pass over all nodes -> rank keys ----
#pragma unroll 2
    for (int c = 0; c < CPT; ++c) {
        int j = c * NT + tid;
        float4 b0 = xs4[j * 2];
        float4 b1 = xs4[j * 2 + 1];          // .w = sq_j
#pragma unroll
        for (int q = 0; q < QB; ++q) {
            float m = dist_m(b0, b1, b1.w, qA[q], qBv[q]);
            if (m <= exq[q] && j != i0 + q) {
                float d2c = fmaxf(sqi[q] + m, 0.f);
                u64 key = ((u64)__float_as_uint(d2c) << 32) | (unsigned)j;
                int p = atomicAdd(&cnt2[q], 1);
                if (p < ECAP2) cand[q][p] = key;
            }
        }
    }
    __syncthreads();

    // ---- selection: wave w -> query w, exact rank-by-counting ----
    {
        const int q = wave;
        const int M = cnt2[q];
        if (M >= K && M <= ECAP2) {
            for (int p = lane; p < M; p += 64) {
                u64 my = cand[q][p];
                int rank = 0;
                for (int m = 0; m < M; ++m)
                    rank += (cand[q][m] < my) ? 1 : 0;
                if (rank < K) nbr[q][rank] = (int)(my & 0xffffffffu);
            }
        }
    }
    __syncthreads();

    // ---- exact fallback (cold, ~never): full sequential extraction ----
#pragma unroll 1
    for (int q = 0; q < QB; ++q) {
        int M = cnt2[q];                     // block-uniform
        if (M < K || M > ECAP2) {
            const int iq = i0 + q;
            const float* xq = x + iq * 8;
            float4 A  = *reinterpret_cast<const float4*>(xq);
            float4 Bv = *reinterpret_cast<const float4*>(xq + 4);
            Bv.w = xs4[iq * 2 + 1].w;        // sq_i
            float lastv = -1.0f; int lasti = -1;
#pragma unroll 1
            for (int it = 0; it < K; ++it) {
                float best = INFINITY; int bidx = 0x7fffffff;
#pragma unroll 1
                for (int c = 0; c < CPT; ++c) {
                    int j = c * NT + tid;
                    float4 b0 = xs4[j * 2];
                    float4 b1 = xs4[j * 2 + 1];
                    float m = dist_m(b0, b1, b1.w, A, Bv);
                    float d2c = fmaxf(Bv.w + m, 0.f);
                    if (j == iq) continue;
                    bool gt = (d2c > lastv) || (d2c == lastv && j > lasti);
                    if (gt && (d2c < best || (d2c == best && j < bidx))) {
                        best = d2c; bidx = j;
                    }
                }
#pragma unroll
                for (int off = 32; off > 0; off >>= 1) {
                    float ov = __shfl_down(best, off);
                    int   oi = __shfl_down(bidx, off);
                    if (ov < best || (ov == best && oi < bidx)) { best = ov; bidx = oi; }
                }
                if (lane == 0) { redv[wave] = best; redi[wave] = bidx; }
                __syncthreads();
                if (tid == 0) {
                    float bv = redv[0]; int bi = redi[0];
#pragma unroll
                    for (int w = 1; w < 8; ++w)
                        if (redv[w] < bv || (redv[w] == bv && redi[w] < bi)) {
                            bv = redv[w]; bi = redi[w];
                        }
                    bcv = bv; bci = bi;
                    nbr[q][it] = bi;
                }
                __syncthreads();
                lastv = bcv; lasti = bci;
            }
        }
    }
    __syncthreads();

    // ---- attention epilogue: wave w -> query w, lanes 0..31 ----
    {
        const int q  = wave;
        const int iq = i0 + q;
        if (lane < K) {
            int nk = nbr[q][lane];
            float s = 0.f;
#pragma unroll
            for (int c = 0; c < D; ++c) s += outb[iq * D + c] * aw[c];
            float xp[D + 1];
#pragma unroll
            for (int c = 0; c < D; ++c) {
                float on = outb[nk * D + c];
                xp[c] = on;
                s += on * aw[D + c];
            }
            xp[D] = x[nk * 8 + 7];

            float m = s;
#pragma unroll
            for (int off = 16; off > 0; off >>= 1) m = fmaxf(m, __shfl_xor(m, off, 32));
            float e = expf(s - m);
            float sum = e;
#pragma unroll
            for (int off = 16; off > 0; off >>= 1) sum += __shfl_xor(sum, off, 32);
            float att = e / sum;

            float agg[D + 1];
#pragma unroll
            for (int dd = 0; dd < D + 1; ++dd) {
                float v = att * xp[dd];
#pragma unroll
                for (int off = 16; off > 0; off >>= 1) v += __shfl_xor(v, off, 32);
                agg[dd] = v;
            }

            if (lane < D) {
                float o = outb[iq * D + lane];
                dout[iq * 15 + lane] = o;
                dout[N_NODES * 15 + iq * 15 + lane] = o;
            }
            if (lane < D + 1) {
                float av_ = agg[0];
#pragma unroll
                for (int dd = 1; dd < D + 1; ++dd) av_ = (lane == dd) ? agg[dd] : av_;
                dout[iq * 15 + D + lane] = av_;
                dout[N_NODES * 15 + iq * 15 + D + lane] = av_;
            }
            if (iq == N_NODES - 1) dout[2 * N_NODES * 15 + lane] = att;
        }
    }
}

extern "C" void kernel_launch(void* const* d_in, const int* in_sizes, int n_in,
                              void* d_out, int out_size, void* d_ws, size_t ws_size,
                              hipStream_t stream) {
    (void)in_sizes; (void)n_in; (void)out_size; (void)ws_size;
    const float* x = (const float*)d_in[0];
    const float* W = (const float*)d_in[1];
    const float* a = (const float*)d_in[2];
    float* out   = (float*)d_out;
    float* outb  = (float*)d_ws;                      // 8192*7 f32 (224 KB)
    uint4* fh    = (uint4*)(outb + N_NODES * D);      // 8192*16 B (128 KB)
    float4* xsq4 = (float4*)(fh + N_NODES);           // 8192*32 B (256 KB)

    hipLaunchKernelGGL(precompute_kernel, dim3(N_NODES / 256), dim3(256),
                       0, stream, x, W, outb, fh, xsq4);
    hipLaunchKernelGGL(gat_kernel, dim3(N_NODES / QB), dim3(NT),
                       0, stream, x, a, outb, fh, xsq4, out);
}